// Round 14
// baseline (1046.004 us; speedup 1.0000x reference)
//
#include <hip/hip_runtime.h>
#include <stdint.h>

// ---------- problem constants ----------
#define DD 768
#define HH 12
#define HDIM 64
#define TT 256
#define BCN 152          // B*C
#define MROWS 38912      // B*N
#define HID 3072

typedef __attribute__((ext_vector_type(8))) short bf16x8;
typedef __attribute__((ext_vector_type(4))) float f32x4;
typedef __attribute__((ext_vector_type(16))) float f32x16;

__device__ __forceinline__ float b2f(unsigned short u) {
  union { unsigned int i; float f; } c; c.i = ((unsigned int)u) << 16; return c.f;
}
__device__ __forceinline__ unsigned short f2b(float f) {
  union { float f; unsigned int i; } c; c.f = f;
  unsigned int x = c.i;
  return (unsigned short)((x + 0x7fffu + ((x >> 16) & 1u)) >> 16);
}

__device__ __forceinline__ void gload16(const unsigned short* g, unsigned short* l) {
  __builtin_amdgcn_global_load_lds(
      (const __attribute__((address_space(1))) void*)g,
      (__attribute__((address_space(3))) void*)l, 16, 0, 0);
}

// ---------- fused prologue: LN1 (blocks 0..9727) + weight cvt (blocks 9728..16639) ----------
__global__ __launch_bounds__(256) void k_pre(const float* __restrict__ x,
                                             const float* __restrict__ w,
                                             const float* __restrict__ b,
                                             unsigned short* __restrict__ hout,
                                             const float* __restrict__ s0,
                                             const float* __restrict__ s1,
                                             const float* __restrict__ s2,
                                             const float* __restrict__ s3,
                                             unsigned short* __restrict__ d0,
                                             unsigned short* __restrict__ d1,
                                             unsigned short* __restrict__ d2,
                                             unsigned short* __restrict__ d3) {
  if (blockIdx.x < 9728) {
    int lane = threadIdx.x & 63;
    int wv = threadIdx.x >> 6;
    size_t row = (size_t)blockIdx.x * 4 + wv;
    const float4* xr = (const float4*)(x + row * DD);
    float4 v0 = xr[lane], v1 = xr[lane + 64], v2 = xr[lane + 128];
    float s = v0.x + v0.y + v0.z + v0.w + v1.x + v1.y + v1.z + v1.w + v2.x + v2.y + v2.z + v2.w;
    float q = v0.x*v0.x + v0.y*v0.y + v0.z*v0.z + v0.w*v0.w
            + v1.x*v1.x + v1.y*v1.y + v1.z*v1.z + v1.w*v1.w
            + v2.x*v2.x + v2.y*v2.y + v2.z*v2.z + v2.w*v2.w;
#pragma unroll
    for (int m = 1; m < 64; m <<= 1) { s += __shfl_xor(s, m, 64); q += __shfl_xor(q, m, 64); }
    float mean = s * (1.0f / 768.0f);
    float var = q * (1.0f / 768.0f) - mean * mean;
    float rstd = rsqrtf(var + 1e-5f);
    ushort4* orow = (ushort4*)(hout + row * DD);
#pragma unroll
    for (int i = 0; i < 3; i++) {
      int idx = lane + i * 64;
      float4 v = (i == 0) ? v0 : (i == 1) ? v1 : v2;
      float4 ww = ((const float4*)w)[idx];
      float4 bb = ((const float4*)b)[idx];
      ushort4 u;
      u.x = f2b((v.x - mean) * rstd * ww.x + bb.x);
      u.y = f2b((v.y - mean) * rstd * ww.y + bb.y);
      u.z = f2b((v.z - mean) * rstd * ww.z + bb.z);
      u.w = f2b((v.w - mean) * rstd * ww.w + bb.w);
      orow[idx] = u;
    }
  } else {
    int i = (blockIdx.x - 9728) * 256 + threadIdx.x;   // < 1769472
    const float* src; unsigned short* dst; int off;
    if (i < 442368)           { src = s0; dst = d0; off = i; }
    else if (i < 589824)      { src = s1; dst = d1; off = i - 442368; }
    else if (i < 1179648)     { src = s2; dst = d2; off = i - 589824; }
    else                      { src = s3; dst = d3; off = i - 1179648; }
    float4 a = ((const float4*)src)[off];
    ushort4 u;
    u.x = f2b(a.x); u.y = f2b(a.y); u.z = f2b(a.z); u.w = f2b(a.w);
    ((ushort4*)dst)[off] = u;
  }
}

// ---------- LayerNorm (fp32 in -> bf16 out), one wave per row of 768 ----------
__global__ __launch_bounds__(256) void k_ln(const float* __restrict__ x,
                                            const float* __restrict__ w,
                                            const float* __restrict__ b,
                                            unsigned short* __restrict__ out) {
  int lane = threadIdx.x & 63;
  int wv = threadIdx.x >> 6;
  size_t row = (size_t)blockIdx.x * 4 + wv;
  const float4* xr = (const float4*)(x + row * DD);
  float4 v0 = xr[lane], v1 = xr[lane + 64], v2 = xr[lane + 128];
  float s = v0.x + v0.y + v0.z + v0.w + v1.x + v1.y + v1.z + v1.w + v2.x + v2.y + v2.z + v2.w;
  float q = v0.x*v0.x + v0.y*v0.y + v0.z*v0.z + v0.w*v0.w
          + v1.x*v1.x + v1.y*v1.y + v1.z*v1.z + v1.w*v1.w
          + v2.x*v2.x + v2.y*v2.y + v2.z*v2.z + v2.w*v2.w;
#pragma unroll
  for (int m = 1; m < 64; m <<= 1) { s += __shfl_xor(s, m, 64); q += __shfl_xor(q, m, 64); }
  float mean = s * (1.0f / 768.0f);
  float var = q * (1.0f / 768.0f) - mean * mean;
  float rstd = rsqrtf(var + 1e-5f);
  ushort4* orow = (ushort4*)(out + row * DD);
#pragma unroll
  for (int i = 0; i < 3; i++) {
    int idx = lane + i * 64;
    float4 v = (i == 0) ? v0 : (i == 1) ? v1 : v2;
    float4 ww = ((const float4*)w)[idx];
    float4 bb = ((const float4*)b)[idx];
    ushort4 u;
    u.x = f2b((v.x - mean) * rstd * ww.x + bb.x);
    u.y = f2b((v.y - mean) * rstd * ww.y + bb.y);
    u.z = f2b((v.z - mean) * rstd * ww.z + bb.z);
    u.w = f2b((v.w - mean) * rstd * ww.w + bb.w);
    orow[idx] = u;
  }
}

// ---------- GEMM: m97 structure + T2 swizzle, 32x32x16 MFMA inner tile ----------
// BM=BN=128, BK=64, 256 thr = 4 waves (2x2), wave quadrant 64x64 = 2x2 of
// 32x32. Per K-tile: 16 ds_read_b128 (same as 16x16 variant) but 16 MFMA of
// 32x32x16 (~129 cyc matrix-pipe) vs 32 of 16x16x32 (~155 cyc) -- the 32x32
// shape is ~15% more FLOP-efficient (2382 vs 2075 TF ubench) at half the
// instruction count. Single-buffered 32 KiB LDS -> 4 blocks/CU (m114 overlap).
// A-frag: row=lane&31, k=(lane>>5)*8. C/D: col=lane&31,
// row=(reg&3)+8*(reg>>2)+4*(lane>>5) [m74/m101-verified mapping].
// MODE 0: bf16 store. MODE 1: +bias +resid -> f32. MODE 2: +bias +GELU -> bf16.
template <int MODE>
__global__ __launch_bounds__(256, 4) void k_gemm9(const unsigned short* __restrict__ A,
                                                  const unsigned short* __restrict__ W,
                                                  const float* __restrict__ bias,
                                                  const float* resid,
                                                  void* outv, int N, int K) {
  __shared__ __align__(16) unsigned short As[128 * 64];
  __shared__ __align__(16) unsigned short Bs[128 * 64];
  const int tid = threadIdx.x;
  const int lane = tid & 63, wv = tid >> 6;
  const int wr = wv >> 1, wc = wv & 1;
  const int l31 = lane & 31, l5 = lane >> 5;

  // T1 bijective XCD swizzle (nwg % 8 == 0 for all our grids)
  const int nbx = gridDim.x;
  const int nwg = nbx * gridDim.y;
  const int flat = blockIdx.y * nbx + blockIdx.x;
  const int swz = (flat & 7) * (nwg >> 3) + (flat >> 3);
  const size_t bm = (size_t)(swz / nbx) * 128;
  const size_t bn = (size_t)(swz % nbx) * 128;
  const unsigned short* Ab = A + bm * K;
  const unsigned short* Wb = W + bn * K;

  f32x16 acc[2][2];
#pragma unroll
  for (int mt = 0; mt < 2; mt++)
#pragma unroll
    for (int nt = 0; nt < 2; nt++)
#pragma unroll
      for (int r = 0; r < 16; r++) acc[mt][nt][r] = 0.f;

  const int nk = K >> 6;
  for (int kt = 0; kt < nk; ++kt) {
    __syncthreads();   // previous iteration's reads complete before overwrite
#pragma unroll
    for (int i = 0; i < 4; i++) {
      int g = i * 256 + tid;            // granule id, linear in lane
      int row = g >> 3;
      int cg = (g & 7) ^ (row & 7);     // inverse-swizzled global source
      gload16(Ab + (size_t)row * K + (size_t)kt * 64 + cg * 8, &As[g * 8]);
      gload16(Wb + (size_t)row * K + (size_t)kt * 64 + cg * 8, &Bs[g * 8]);
    }
    __syncthreads();   // compiler drains vmcnt(0) before barrier -> tile visible
#pragma unroll
    for (int ks = 0; ks < 4; ++ks) {
      int gk = ks * 2 + l5;             // granule index of this lane's 8 k-elems
      bf16x8 af[2], bfr[2];
#pragma unroll
      for (int mt = 0; mt < 2; mt++) {
        int row = wr * 64 + mt * 32 + l31;
        af[mt] = *(const bf16x8*)&As[row * 64 + ((gk ^ (row & 7)) * 8)];
      }
#pragma unroll
      for (int nt = 0; nt < 2; nt++) {
        int row = wc * 64 + nt * 32 + l31;
        bfr[nt] = *(const bf16x8*)&Bs[row * 64 + ((gk ^ (row & 7)) * 8)];
      }
#pragma unroll
      for (int mt = 0; mt < 2; mt++)
#pragma unroll
        for (int nt = 0; nt < 2; nt++)
          acc[mt][nt] = __builtin_amdgcn_mfma_f32_32x32x16_bf16(af[mt], bfr[nt], acc[mt][nt], 0, 0, 0);
    }
  }

  // epilogue: col = bn + wc*64 + nt*32 + l31;
  //           row = bm + wr*64 + mt*32 + (reg&3) + 8*(reg>>2) + 4*l5
#pragma unroll
  for (int mt = 0; mt < 2; mt++) {
#pragma unroll
    for (int nt = 0; nt < 2; nt++) {
      size_t col = bn + wc * 64 + nt * 32 + l31;
#pragma unroll
      for (int reg = 0; reg < 16; reg++) {
        size_t row = bm + wr * 64 + mt * 32 + (reg & 3) + 8 * (reg >> 2) + 4 * l5;
        float v = acc[mt][nt][reg];
        if (MODE == 0) {
          ((unsigned short*)outv)[row * N + col] = f2b(v);
        } else if (MODE == 1) {
          v += bias[col] + resid[row * N + col];
          ((float*)outv)[row * N + col] = v;
        } else {
          v += bias[col];
          float g = 0.5f * v * (1.0f + erff(v * 0.70710678118654752f));
          ((unsigned short*)outv)[row * N + col] = f2b(g);
        }
      }
    }
  }
}

// ---------- attention v3: block = (head, bc, q-quarter); 4 waves x 16 Q rows ----------
// 256 thr, 32 KiB LDS, (256,4). No setprio (4-wave lockstep = m190 null regime).
__global__ __launch_bounds__(256, 4) void k_attn(const unsigned short* __restrict__ qkv,
                                                 unsigned short* __restrict__ o) {
  __shared__ __align__(16) unsigned short Kc[2][64 * 64];   // 16 KiB
  __shared__ __align__(16) unsigned short Vt[64 * 64];      // 8 KiB
  __shared__ __align__(16) unsigned short Pl[4][16 * 64];   // 8 KiB
  const int h = blockIdx.x, bc = blockIdx.y, qz = blockIdx.z;
  const int tid = threadIdx.x;
  const int lane = tid & 63, wv = tid >> 6;    // 4 waves
  const int cl = lane & 15, hi = lane >> 4;
  const int qb = qz * 64 + wv * 16;            // this wave's 16 q-rows

  bf16x8 qf[2];
#pragma unroll
  for (int ks = 0; ks < 2; ks++) {
    size_t row = (size_t)bc * 256 + qb + cl;
    bf16x8 raw = *(const bf16x8*)(qkv + row * 2304 + h * 64 + ks * 32 + hi * 8);
    bf16x8 sc;
#pragma unroll
    for (int jx = 0; jx < 8; jx++) sc[jx] = (short)f2b(0.125f * b2f((unsigned short)raw[jx]));
    qf[ks] = sc;
  }

  f32x4 oacc[4];
#pragma unroll
  for (int n = 0; n < 4; n++) oacc[n] = (f32x4){0.f, 0.f, 0.f, 0.f};
  float mrun[4], lrun[4];
#pragma unroll
  for (int r = 0; r < 4; r++) { mrun[r] = -1e30f; lrun[r] = 0.f; }

  auto stageK = [&](int j, int buf) {
#pragma unroll
    for (int i = 0; i < 2; i++) {
      int idx = i * 256 + tid;
      int tok = idx >> 3, c8 = idx & 7;
      size_t gtok = (size_t)bc * 256 + j * 64 + tok;
      gload16(qkv + gtok * 2304 + 768 + h * 64 + ((c8 ^ (tok & 7)) * 8), &Kc[buf][idx * 8]);
    }
  };
  uint4 vreg[2];
  auto loadV = [&](int j) {
#pragma unroll
    for (int i = 0; i < 2; i++) {
      int idx = i * 256 + tid;
      int tok = idx >> 3, c8 = idx & 7;
      size_t gtok = (size_t)bc * 256 + j * 64 + tok;
      vreg[i] = *(const uint4*)(qkv + gtok * 2304 + 1536 + h * 64 + c8 * 8);
    }
  };
  auto writeV = [&]() {
#pragma unroll
    for (int i = 0; i < 2; i++) {
      int idx = i * 256 + tid;
      int tok = idx >> 3, c8 = idx & 7;
      union { uint4 u4; unsigned short us[8]; } cv; cv.u4 = vreg[i];
#pragma unroll
      for (int jj = 0; jj < 8; jj++) {
        int d = c8 * 8 + jj;
        int g = ((tok >> 3) ^ (d & 7) ^ ((d >> 3) & 7)) & 7;
        Vt[d * 64 + g * 8 + (tok & 7)] = cv.us[jj];
      }
    }
  };

  stageK(0, 0);
  loadV(0);

  for (int j = 0; j < 4; j++) {
    __syncthreads();   // drains vm+lgkm: Kc[j&1] published, vreg ready

    f32x4 s[4];
#pragma unroll
    for (int n = 0; n < 4; n++) s[n] = (f32x4){0.f, 0.f, 0.f, 0.f};
#pragma unroll
    for (int ks = 0; ks < 2; ++ks) {
      bf16x8 kf[4];
#pragma unroll
      for (int n = 0; n < 4; n++) {
        int row = n * 16 + cl;
        kf[n] = *(const bf16x8*)&Kc[j & 1][row * 64 + (((ks * 4 + hi) ^ (row & 7)) * 8)];
      }
#pragma unroll
      for (int n = 0; n < 4; n++)
        s[n] = __builtin_amdgcn_mfma_f32_16x16x32_bf16(qf[ks], kf[n], s[n], 0, 0, 0);
    }

    stageK((j + 1) & 3, (j + 1) & 1);

#pragma unroll
    for (int r = 0; r < 4; r++) {
      float pm = fmaxf(fmaxf(s[0][r], s[1][r]), fmaxf(s[2][r], s[3][r]));
#pragma unroll
      for (int xm = 1; xm < 16; xm <<= 1) pm = fmaxf(pm, __shfl_xor(pm, xm, 64));
      float nm = fmaxf(mrun[r], pm);
      float fac = __expf(mrun[r] - nm);
      mrun[r] = nm;
      float ps = 0.f;
#pragma unroll
      for (int n = 0; n < 4; n++) {
        float e = __expf(s[n][r] - nm);
        s[n][r] = e;
        ps += e;
      }
#pragma unroll
      for (int xm = 1; xm < 16; xm <<= 1) ps += __shfl_xor(ps, xm, 64);
      lrun[r] = lrun[r] * fac + ps;
#pragma unroll
      for (int n2 = 0; n2 < 4; n2++) oacc[n2][r] *= fac;
    }

    writeV();
    loadV((j + 1) & 3);
    __syncthreads();   // drains ds_writes + K prefetch; Vt + Kc[(j+1)&1] published

    bf16x8 pv[2][4];
#pragma unroll
    for (int ks = 0; ks < 2; ks++)
#pragma unroll
      for (int n = 0; n < 4; n++) {
        int d = n * 16 + cl;
        pv[ks][n] = *(const bf16x8*)&Vt[d * 64 + ((((ks * 4 + hi) ^ (d & 7) ^ ((d >> 3) & 7)) & 7) * 8)];
      }
#pragma unroll
    for (int n = 0; n < 4; n++)
#pragma unroll
      for (int r = 0; r < 4; r++) {
        int q = hi * 4 + r;
        int g = ((n * 2 + (cl >> 3)) ^ (q & 7) ^ (q >> 3)) & 7;
        Pl[wv][q * 64 + g * 8 + (cl & 7)] = f2b(s[n][r]);
      }
    asm volatile("s_waitcnt lgkmcnt(0)" ::: "memory");
    __builtin_amdgcn_sched_barrier(0);
    bf16x8 pa0 = *(const bf16x8*)&Pl[wv][cl * 64 + (((hi ^ (cl & 7) ^ (cl >> 3)) & 7) * 8)];
    bf16x8 pa1 = *(const bf16x8*)&Pl[wv][cl * 64 + ((((4 + hi) ^ (cl & 7) ^ (cl >> 3)) & 7) * 8)];
#pragma unroll
    for (int n = 0; n < 4; n++)
      oacc[n] = __builtin_amdgcn_mfma_f32_16x16x32_bf16(pa0, pv[0][n], oacc[n], 0, 0, 0);
#pragma unroll
    for (int n = 0; n < 4; n++)
      oacc[n] = __builtin_amdgcn_mfma_f32_16x16x32_bf16(pa1, pv[1][n], oacc[n], 0, 0, 0);
  }

#pragma unroll
  for (int r = 0; r < 4; r++) {
    float inv = 1.0f / lrun[r];
    size_t row = (size_t)bc * 256 + qb + hi * 4 + r;
#pragma unroll
    for (int n = 0; n < 4; n++)
      o[row * DD + h * 64 + n * 16 + cl] = f2b(oacc[n][r] * inv);
  }
}

extern "C" void kernel_launch(void* const* d_in, const int* in_sizes, int n_in,
                              void* d_out, int out_size, void* d_ws, size_t ws_size,
                              hipStream_t stream) {
  const float* x     = (const float*)d_in[0];
  const float* n1w   = (const float*)d_in[1];
  const float* n1b   = (const float*)d_in[2];
  const float* qkvw  = (const float*)d_in[3];
  const float* projw = (const float*)d_in[4];
  const float* projb = (const float*)d_in[5];
  const float* n2w   = (const float*)d_in[6];
  const float* n2b   = (const float*)d_in[7];
  const float* fc1w  = (const float*)d_in[8];
  const float* fc1b  = (const float*)d_in[9];
  const float* fc2w  = (const float*)d_in[10];
  const float* fc2b  = (const float*)d_in[11];
  float* out = (float*)d_out;

  const size_t NEED = 312999936ull;
  if (ws_size < NEED) return;
  char* ws = (char*)d_ws;
  unsigned short* h   = (unsigned short*)(ws);
  unsigned short* qkv = (unsigned short*)(ws + 59768832ull);
  unsigned short* ob  = (unsigned short*)(ws + 239075328ull);
  unsigned short* act = (unsigned short*)(ws + 59768832ull);
  unsigned short* wq  = (unsigned short*)(ws + 298844160ull);
  unsigned short* wp  = wq + 2304 * 768;
  unsigned short* w1  = wp + 768 * 768;
  unsigned short* w2  = w1 + 3072 * 768;

  // fused prologue: LN1 (9728 blocks) + all weight converts (6912 blocks)
  k_pre<<<9728 + 6912, 256, 0, stream>>>(x, n1w, n1b, h,
                                         qkvw, projw, fc1w, fc2w, wq, wp, w1, w2);
  // QKV: (38912x768) @ (2304x768)^T -> bf16
  k_gemm9<0><<<dim3(2304 / 128, MROWS / 128), 256, 0, stream>>>(h, wq, nullptr, nullptr, qkv, 2304, 768);
  // attention (4 q-quarters per (h, bc))
  k_attn<<<dim3(HH, BCN, 4), 256, 0, stream>>>(qkv, ob);
  // proj + bias + residual(x) -> y in d_out (fp32)
  k_gemm9<1><<<dim3(768 / 128, MROWS / 128), 256, 0, stream>>>(ob, wp, projb, x, out, 768, 768);
  // LN2 on y
  k_ln<<<MROWS / 4, 256, 0, stream>>>(out, n2w, n2b, h);
  // FC1 + bias + exact GELU -> bf16 act
  k_gemm9<2><<<dim3(3072 / 128, MROWS / 128), 256, 0, stream>>>(h, w1, fc1b, nullptr, act, 3072, 768);
  // FC2 + bias + residual(y) -> d_out (fp32)
  k_gemm9<1><<<dim3(768 / 128, MROWS / 128), 256, 0, stream>>>(act, w2, fc2b, out, out, 768, 3072);
}

// Round 15
// 995.265 us; speedup vs baseline: 1.0510x; 1.0510x over previous
//
#include <hip/hip_runtime.h>
#include <stdint.h>

// ---------- problem constants ----------
#define DD 768
#define HH 12
#define HDIM 64
#define TT 256
#define BCN 152          // B*C
#define MROWS 38912      // B*N
#define HID 3072

typedef __attribute__((ext_vector_type(8))) short bf16x8;
typedef __attribute__((ext_vector_type(4))) float f32x4;

__device__ __forceinline__ float b2f(unsigned short u) {
  union { unsigned int i; float f; } c; c.i = ((unsigned int)u) << 16; return c.f;
}
__device__ __forceinline__ unsigned short f2b(float f) {
  union { float f; unsigned int i; } c; c.f = f;
  unsigned int x = c.i;
  return (unsigned short)((x + 0x7fffu + ((x >> 16) & 1u)) >> 16);
}

__device__ __forceinline__ void gload16(const unsigned short* g, unsigned short* l) {
  __builtin_amdgcn_global_load_lds(
      (const __attribute__((address_space(1))) void*)g,
      (__attribute__((address_space(3))) void*)l, 16, 0, 0);
}

// ---------- fused fp32 -> bf16 weight convert (all 4 weight tensors) ----------
// segments (in float4 units): qkv 442368 | proj 147456 | fc1 589824 | fc2 589824
__global__ __launch_bounds__(256) void k_cvt4(const float* __restrict__ s0,
                                              const float* __restrict__ s1,
                                              const float* __restrict__ s2,
                                              const float* __restrict__ s3,
                                              unsigned short* __restrict__ d0,
                                              unsigned short* __restrict__ d1,
                                              unsigned short* __restrict__ d2,
                                              unsigned short* __restrict__ d3) {
  int i = blockIdx.x * 256 + threadIdx.x;   // < 1769472
  const float* src; unsigned short* dst; int off;
  if (i < 442368)           { src = s0; dst = d0; off = i; }
  else if (i < 589824)      { src = s1; dst = d1; off = i - 442368; }
  else if (i < 1179648)     { src = s2; dst = d2; off = i - 589824; }
  else                      { src = s3; dst = d3; off = i - 1179648; }
  float4 a = ((const float4*)src)[off];
  ushort4 u;
  u.x = f2b(a.x); u.y = f2b(a.y); u.z = f2b(a.z); u.w = f2b(a.w);
  ((ushort4*)dst)[off] = u;
}

// ---------- LayerNorm (fp32 in -> bf16 out), one wave per row of 768 ----------
__global__ __launch_bounds__(256) void k_ln(const float* __restrict__ x,
                                            const float* __restrict__ w,
                                            const float* __restrict__ b,
                                            unsigned short* __restrict__ out) {
  int lane = threadIdx.x & 63;
  int wv = threadIdx.x >> 6;
  size_t row = (size_t)blockIdx.x * 4 + wv;
  const float4* xr = (const float4*)(x + row * DD);
  float4 v0 = xr[lane], v1 = xr[lane + 64], v2 = xr[lane + 128];
  float s = v0.x + v0.y + v0.z + v0.w + v1.x + v1.y + v1.z + v1.w + v2.x + v2.y + v2.z + v2.w;
  float q = v0.x*v0.x + v0.y*v0.y + v0.z*v0.z + v0.w*v0.w
          + v1.x*v1.x + v1.y*v1.y + v1.z*v1.z + v1.w*v1.w
          + v2.x*v2.x + v2.y*v2.y + v2.z*v2.z + v2.w*v2.w;
#pragma unroll
  for (int m = 1; m < 64; m <<= 1) { s += __shfl_xor(s, m, 64); q += __shfl_xor(q, m, 64); }
  float mean = s * (1.0f / 768.0f);
  float var = q * (1.0f / 768.0f) - mean * mean;
  float rstd = rsqrtf(var + 1e-5f);
  ushort4* orow = (ushort4*)(out + row * DD);
#pragma unroll
  for (int i = 0; i < 3; i++) {
    int idx = lane + i * 64;
    float4 v = (i == 0) ? v0 : (i == 1) ? v1 : v2;
    float4 ww = ((const float4*)w)[idx];
    float4 bb = ((const float4*)b)[idx];
    ushort4 u;
    u.x = f2b((v.x - mean) * rstd * ww.x + bb.x);
    u.y = f2b((v.y - mean) * rstd * ww.y + bb.y);
    u.z = f2b((v.z - mean) * rstd * ww.z + bb.z);
    u.w = f2b((v.w - mean) * rstd * ww.w + bb.w);
    orow[idx] = u;
  }
}

// ---------- m97-structure GEMM + T2 swizzle: out[M,N] = A[M,K] @ W[N,K]^T ----------
// BM=BN=128, BK=64, 256 thr = 4 waves (2x2), wave quadrant 64x64, acc 4x4.
// Single-buffered 32 KiB LDS -> 4 blocks/CU (implicit cross-block MFMA/stage
// overlap, m114). Both-sides XOR swizzle on 16B granules (conflict-free reads,
// verified 0 in rounds 7/9/10/12/13). Do NOT perturb: five pipelining variants
// (r3,4,5,8,11) and the 32x32x16 inner tile (r14, 8-way bank conflict: bank set
// of ds_read_b128 at 128B rows depends only on granule index) all regressed.
// MODE 0: bf16 store. MODE 1: +bias +resid -> f32. MODE 2: +bias +GELU -> bf16.
template <int MODE>
__global__ __launch_bounds__(256, 4) void k_gemm6(const unsigned short* __restrict__ A,
                                                  const unsigned short* __restrict__ W,
                                                  const float* __restrict__ bias,
                                                  const float* resid,
                                                  void* outv, int N, int K) {
  __shared__ __align__(16) unsigned short As[128 * 64];
  __shared__ __align__(16) unsigned short Bs[128 * 64];
  const int tid = threadIdx.x;
  const int lane = tid & 63, wv = tid >> 6;
  const int wr = wv >> 1, wc = wv & 1;
  const int cl = lane & 15, hi = lane >> 4;

  // T1 bijective XCD swizzle (nwg % 8 == 0 for all our grids)
  const int nbx = gridDim.x;
  const int nwg = nbx * gridDim.y;
  const int flat = blockIdx.y * nbx + blockIdx.x;
  const int swz = (flat & 7) * (nwg >> 3) + (flat >> 3);
  const size_t bm = (size_t)(swz / nbx) * 128;
  const size_t bn = (size_t)(swz % nbx) * 128;
  const unsigned short* Ab = A + bm * K;
  const unsigned short* Wb = W + bn * K;

  f32x4 acc[4][4];
#pragma unroll
  for (int m = 0; m < 4; m++)
#pragma unroll
    for (int n = 0; n < 4; n++) acc[m][n] = (f32x4){0.f, 0.f, 0.f, 0.f};

  const int nk = K >> 6;
  for (int kt = 0; kt < nk; ++kt) {
    __syncthreads();   // previous iteration's reads complete before overwrite
#pragma unroll
    for (int i = 0; i < 4; i++) {
      int g = i * 256 + tid;            // granule id, linear in lane
      int row = g >> 3;
      int cg = (g & 7) ^ (row & 7);     // inverse-swizzled global source
      gload16(Ab + (size_t)row * K + (size_t)kt * 64 + cg * 8, &As[g * 8]);
      gload16(Wb + (size_t)row * K + (size_t)kt * 64 + cg * 8, &Bs[g * 8]);
    }
    __syncthreads();   // compiler drains vmcnt(0) before barrier -> tile visible
#pragma unroll
    for (int ks = 0; ks < 2; ++ks) {
      bf16x8 af[4], bfr[4];
#pragma unroll
      for (int m = 0; m < 4; m++) {
        int row = wr * 64 + m * 16 + cl;
        af[m] = *(const bf16x8*)&As[row * 64 + (((ks * 4 + hi) ^ (row & 7)) * 8)];
      }
#pragma unroll
      for (int n = 0; n < 4; n++) {
        int row = wc * 64 + n * 16 + cl;
        bfr[n] = *(const bf16x8*)&Bs[row * 64 + (((ks * 4 + hi) ^ (row & 7)) * 8)];
      }
#pragma unroll
      for (int m = 0; m < 4; m++)
#pragma unroll
        for (int n = 0; n < 4; n++)
          acc[m][n] = __builtin_amdgcn_mfma_f32_16x16x32_bf16(af[m], bfr[n], acc[m][n], 0, 0, 0);
    }
  }

#pragma unroll
  for (int m = 0; m < 4; m++) {
#pragma unroll
    for (int n = 0; n < 4; n++) {
      size_t col = bn + wc * 64 + n * 16 + cl;
#pragma unroll
      for (int r = 0; r < 4; r++) {
        size_t row = bm + wr * 64 + m * 16 + hi * 4 + r;
        float v = acc[m][n][r];
        if (MODE == 0) {
          ((unsigned short*)outv)[row * N + col] = f2b(v);
        } else if (MODE == 1) {
          v += bias[col] + resid[row * N + col];
          ((float*)outv)[row * N + col] = v;
        } else {
          v += bias[col];
          float g = 0.5f * v * (1.0f + erff(v * 0.70710678118654752f));
          ((unsigned short*)outv)[row * N + col] = f2b(g);
        }
      }
    }
  }
}

// ---------- attention v3: block = (head, bc, q-quarter); 4 waves x 16 Q rows ----------
// 256 thr, 32 KiB LDS, (256,4) [(256,5) spilled: round-10 regression].
// K via gload16 (linear dest, pre-swizzled src) + swizzled ds_read_b128;
// V reg-staged, transposed swizzled write; P in per-wave swizzled slab.
// No setprio (4-wave lockstep = m190 null regime; r13 confirmed negative).
__global__ __launch_bounds__(256, 4) void k_attn(const unsigned short* __restrict__ qkv,
                                                 unsigned short* __restrict__ o) {
  __shared__ __align__(16) unsigned short Kc[2][64 * 64];   // 16 KiB
  __shared__ __align__(16) unsigned short Vt[64 * 64];      // 8 KiB
  __shared__ __align__(16) unsigned short Pl[4][16 * 64];   // 8 KiB
  const int h = blockIdx.x, bc = blockIdx.y, qz = blockIdx.z;
  const int tid = threadIdx.x;
  const int lane = tid & 63, wv = tid >> 6;    // 4 waves
  const int cl = lane & 15, hi = lane >> 4;
  const int qb = qz * 64 + wv * 16;            // this wave's 16 q-rows

  // Q fragments (16 rows), scaled by 0.125 (exact in bf16)
  bf16x8 qf[2];
#pragma unroll
  for (int ks = 0; ks < 2; ks++) {
    size_t row = (size_t)bc * 256 + qb + cl;
    bf16x8 raw = *(const bf16x8*)(qkv + row * 2304 + h * 64 + ks * 32 + hi * 8);
    bf16x8 sc;
#pragma unroll
    for (int jx = 0; jx < 8; jx++) sc[jx] = (short)f2b(0.125f * b2f((unsigned short)raw[jx]));
    qf[ks] = sc;
  }

  f32x4 oacc[4];
#pragma unroll
  for (int n = 0; n < 4; n++) oacc[n] = (f32x4){0.f, 0.f, 0.f, 0.f};
  float mrun[4], lrun[4];
#pragma unroll
  for (int r = 0; r < 4; r++) { mrun[r] = -1e30f; lrun[r] = 0.f; }

  auto stageK = [&](int j, int buf) {
#pragma unroll
    for (int i = 0; i < 2; i++) {
      int idx = i * 256 + tid;
      int tok = idx >> 3, c8 = idx & 7;
      size_t gtok = (size_t)bc * 256 + j * 64 + tok;
      gload16(qkv + gtok * 2304 + 768 + h * 64 + ((c8 ^ (tok & 7)) * 8), &Kc[buf][idx * 8]);
    }
  };
  uint4 vreg[2];
  auto loadV = [&](int j) {
#pragma unroll
    for (int i = 0; i < 2; i++) {
      int idx = i * 256 + tid;
      int tok = idx >> 3, c8 = idx & 7;
      size_t gtok = (size_t)bc * 256 + j * 64 + tok;
      vreg[i] = *(const uint4*)(qkv + gtok * 2304 + 1536 + h * 64 + c8 * 8);
    }
  };
  auto writeV = [&]() {
#pragma unroll
    for (int i = 0; i < 2; i++) {
      int idx = i * 256 + tid;
      int tok = idx >> 3, c8 = idx & 7;
      union { uint4 u4; unsigned short us[8]; } cv; cv.u4 = vreg[i];
#pragma unroll
      for (int jj = 0; jj < 8; jj++) {
        int d = c8 * 8 + jj;
        int g = ((tok >> 3) ^ (d & 7) ^ ((d >> 3) & 7)) & 7;
        Vt[d * 64 + g * 8 + (tok & 7)] = cv.us[jj];
      }
    }
  };

  stageK(0, 0);
  loadV(0);

  for (int j = 0; j < 4; j++) {
    __syncthreads();   // drains vm+lgkm: Kc[j&1] published, vreg ready

    f32x4 s[4];
#pragma unroll
    for (int n = 0; n < 4; n++) s[n] = (f32x4){0.f, 0.f, 0.f, 0.f};
#pragma unroll
    for (int ks = 0; ks < 2; ++ks) {
      bf16x8 kf[4];
#pragma unroll
      for (int n = 0; n < 4; n++) {
        int row = n * 16 + cl;
        kf[n] = *(const bf16x8*)&Kc[j & 1][row * 64 + (((ks * 4 + hi) ^ (row & 7)) * 8)];
      }
#pragma unroll
      for (int n = 0; n < 4; n++)
        s[n] = __builtin_amdgcn_mfma_f32_16x16x32_bf16(qf[ks], kf[n], s[n], 0, 0, 0);
    }

    stageK((j + 1) & 3, (j + 1) & 1);

#pragma unroll
    for (int r = 0; r < 4; r++) {
      float pm = fmaxf(fmaxf(s[0][r], s[1][r]), fmaxf(s[2][r], s[3][r]));
#pragma unroll
      for (int xm = 1; xm < 16; xm <<= 1) pm = fmaxf(pm, __shfl_xor(pm, xm, 64));
      float nm = fmaxf(mrun[r], pm);
      float fac = __expf(mrun[r] - nm);
      mrun[r] = nm;
      float ps = 0.f;
#pragma unroll
      for (int n = 0; n < 4; n++) {
        float e = __expf(s[n][r] - nm);
        s[n][r] = e;
        ps += e;
      }
#pragma unroll
      for (int xm = 1; xm < 16; xm <<= 1) ps += __shfl_xor(ps, xm, 64);
      lrun[r] = lrun[r] * fac + ps;
#pragma unroll
      for (int n2 = 0; n2 < 4; n2++) oacc[n2][r] *= fac;
    }

    writeV();
    loadV((j + 1) & 3);
    __syncthreads();   // drains ds_writes + K prefetch; Vt + Kc[(j+1)&1] published

    bf16x8 pv[2][4];
#pragma unroll
    for (int ks = 0; ks < 2; ks++)
#pragma unroll
      for (int n = 0; n < 4; n++) {
        int d = n * 16 + cl;
        pv[ks][n] = *(const bf16x8*)&Vt[d * 64 + ((((ks * 4 + hi) ^ (d & 7) ^ ((d >> 3) & 7)) & 7) * 8)];
      }
#pragma unroll
    for (int n = 0; n < 4; n++)
#pragma unroll
      for (int r = 0; r < 4; r++) {
        int q = hi * 4 + r;
        int g = ((n * 2 + (cl >> 3)) ^ (q & 7) ^ (q >> 3)) & 7;
        Pl[wv][q * 64 + g * 8 + (cl & 7)] = f2b(s[n][r]);
      }
    asm volatile("s_waitcnt lgkmcnt(0)" ::: "memory");
    __builtin_amdgcn_sched_barrier(0);
    bf16x8 pa0 = *(const bf16x8*)&Pl[wv][cl * 64 + (((hi ^ (cl & 7) ^ (cl >> 3)) & 7) * 8)];
    bf16x8 pa1 = *(const bf16x8*)&Pl[wv][cl * 64 + ((((4 + hi) ^ (cl & 7) ^ (cl >> 3)) & 7) * 8)];
#pragma unroll
    for (int n = 0; n < 4; n++)
      oacc[n] = __builtin_amdgcn_mfma_f32_16x16x32_bf16(pa0, pv[0][n], oacc[n], 0, 0, 0);
#pragma unroll
    for (int n = 0; n < 4; n++)
      oacc[n] = __builtin_amdgcn_mfma_f32_16x16x32_bf16(pa1, pv[1][n], oacc[n], 0, 0, 0);
  }

#pragma unroll
  for (int r = 0; r < 4; r++) {
    float inv = 1.0f / lrun[r];
    size_t row = (size_t)bc * 256 + qb + hi * 4 + r;
#pragma unroll
    for (int n = 0; n < 4; n++)
      o[row * DD + h * 64 + n * 16 + cl] = f2b(oacc[n][r] * inv);
  }
}

extern "C" void kernel_launch(void* const* d_in, const int* in_sizes, int n_in,
                              void* d_out, int out_size, void* d_ws, size_t ws_size,
                              hipStream_t stream) {
  const float* x     = (const float*)d_in[0];
  const float* n1w   = (const float*)d_in[1];
  const float* n1b   = (const float*)d_in[2];
  const float* qkvw  = (const float*)d_in[3];
  const float* projw = (const float*)d_in[4];
  const float* projb = (const float*)d_in[5];
  const float* n2w   = (const float*)d_in[6];
  const float* n2b   = (const float*)d_in[7];
  const float* fc1w  = (const float*)d_in[8];
  const float* fc1b  = (const float*)d_in[9];
  const float* fc2w  = (const float*)d_in[10];
  const float* fc2b  = (const float*)d_in[11];
  float* out = (float*)d_out;

  const size_t NEED = 312999936ull;
  if (ws_size < NEED) return;
  char* ws = (char*)d_ws;
  unsigned short* h   = (unsigned short*)(ws);
  unsigned short* qkv = (unsigned short*)(ws + 59768832ull);
  unsigned short* ob  = (unsigned short*)(ws + 239075328ull);
  unsigned short* act = (unsigned short*)(ws + 59768832ull);
  unsigned short* wq  = (unsigned short*)(ws + 298844160ull);
  unsigned short* wp  = wq + 2304 * 768;
  unsigned short* w1  = wp + 768 * 768;
  unsigned short* w2  = w1 + 3072 * 768;

  // convert all weights to bf16 (single fused launch; 1769472 float4s)
  k_cvt4<<<6912, 256, 0, stream>>>(qkvw, projw, fc1w, fc2w, wq, wp, w1, w2);

  // LN1
  k_ln<<<MROWS / 4, 256, 0, stream>>>(x, n1w, n1b, h);
  // QKV: (38912x768) @ (2304x768)^T -> bf16
  k_gemm6<0><<<dim3(2304 / 128, MROWS / 128), 256, 0, stream>>>(h, wq, nullptr, nullptr, qkv, 2304, 768);
  // attention (4 q-quarters per (h, bc))
  k_attn<<<dim3(HH, BCN, 4), 256, 0, stream>>>(qkv, ob);
  // proj + bias + residual(x) -> y in d_out (fp32)
  k_gemm6<1><<<dim3(768 / 128, MROWS / 128), 256, 0, stream>>>(ob, wp, projb, x, out, 768, 768);
  // LN2 on y
  k_ln<<<MROWS / 4, 256, 0, stream>>>(out, n2w, n2b, h);
  // FC1 + bias + exact GELU -> bf16 act
  k_gemm6<2><<<dim3(3072 / 128, MROWS / 128), 256, 0, stream>>>(h, w1, fc1b, nullptr, act, 3072, 768);
  // FC2 + bias + residual(y) -> d_out (fp32)
  k_gemm6<1><<<dim3(768 / 128, MROWS / 128), 256, 0, stream>>>(act, w2, fc2b, out, out, 768, 3072);
}